// Round 10
// baseline (479.687 us; speedup 1.0000x reference)
//
#include <hip/hip_runtime.h>
#include <hip/hip_bf16.h>
#include <type_traits>

#define NN 20000      // nodes
#define NE 320000     // edges
#define HD 256        // hidden dim
#define NB 2          // batch
#define FIN 128
#define MP 40064      // NB*NN padded to multiple of 128 (313*128)
#define SB 79         // scan blocks = ceil(NN/256)

typedef __attribute__((ext_vector_type(8))) short bf16x8;
typedef __attribute__((ext_vector_type(4))) float f32x4;
typedef __attribute__((ext_vector_type(2))) float f32x2;

__device__ inline ushort f2bf(float f) {
    __hip_bfloat16 h = __float2bfloat16(f);
    return *reinterpret_cast<ushort*>(&h);
}
// fp8 e4m3 (OCP on gfx950) helpers
__device__ inline unsigned int pk4_fp8(float a, float b, float c, float d) {
    int r = __builtin_amdgcn_cvt_pk_fp8_f32(a, b, 0, false);
    r = __builtin_amdgcn_cvt_pk_fp8_f32(c, d, r, true);
    return (unsigned int)r;
}
__device__ inline void acc4_fp8(float* acc, unsigned int u, float w) {
    f32x2 lo = __builtin_amdgcn_cvt_pk_f32_fp8((int)u, false);
    f32x2 hi = __builtin_amdgcn_cvt_pk_f32_fp8((int)u, true);
    acc[0] += w * lo[0]; acc[1] += w * lo[1];
    acc[2] += w * hi[0]; acc[3] += w * hi[1];
}
__device__ inline unsigned char f2fp8(float v) {
    return (unsigned char)(__builtin_amdgcn_cvt_pk_fp8_f32(v, v, 0, false) & 0xff);
}

// ---------------- count incoming edges per dst ----------------
__global__ __launch_bounds__(256) void count_kernel(const int* __restrict__ dst, int* cnt) {
    int e = blockIdx.x * 256 + threadIdx.x;
    if (e < NE) atomicAdd(&cnt[dst[e]], 1);
}

// ---------------- scan stage 1: per-block sums + dinv ----------------
__global__ __launch_bounds__(256) void scan_blk_kernel(const int* __restrict__ cnt,
                                                       int* __restrict__ bsum,
                                                       float* __restrict__ dinv) {
    __shared__ int s[256];
    int t = threadIdx.x, b = blockIdx.x;
    int n = b * 256 + t;
    int c = (n < NN) ? cnt[n] : 0;
    if (n < NN) dinv[n] = rsqrtf(1.0f + (float)c);
    s[t] = c;
    __syncthreads();
    for (int off = 128; off; off >>= 1) {
        if (t < off) s[t] += s[t + off];
        __syncthreads();
    }
    if (t == 0) bsum[b] = s[0];
}

// ---------------- scan stage 2: block offset + intra-block exclusive scan ----------------
__global__ __launch_bounds__(256) void scan_fin_kernel(const int* __restrict__ bsum,
                                                       int* __restrict__ cnt,
                                                       int* __restrict__ rstart) {
    __shared__ int sb[128];
    __shared__ int s[256];
    int t = threadIdx.x, b = blockIdx.x;
    if (t < 128) sb[t] = (t < SB) ? bsum[t] : 0;
    __syncthreads();
    for (int off = 1; off < 128; off <<= 1) {
        int v = (t < 128 && t >= off) ? sb[t - off] : 0;
        __syncthreads();
        if (t < 128) sb[t] += v;
        __syncthreads();
    }
    int boff = (b == 0) ? 0 : sb[b - 1];
    int n = b * 256 + t;
    int c = (n < NN) ? cnt[n] : 0;
    s[t] = c;
    __syncthreads();
    for (int off = 1; off < 256; off <<= 1) {
        int v = (t >= off) ? s[t - off] : 0;
        __syncthreads();
        s[t] += v;
        __syncthreads();
    }
    int excl = s[t] - c + boff;
    if (n < NN) { rstart[n] = excl; cnt[n] = excl; }   // cnt becomes bucket cursor
    if (b == 0 && t == 0) rstart[NN] = NE;
}

// ---------------- bucket edges by dst, precompute weights ----------------
__global__ __launch_bounds__(256) void bucket_kernel(const int* __restrict__ src,
                                                     const int* __restrict__ dst,
                                                     int* cursor, int2* edge2,
                                                     const float* __restrict__ dinv) {
    int e = blockIdx.x * 256 + threadIdx.x;
    if (e >= NE) return;
    int s = src[e], d = dst[e];
    int pos = atomicAdd(&cursor[d], 1);
    float w = dinv[s] * dinv[d];
    edge2[pos] = make_int2(s, __float_as_int(w));
}

// ---------------- fused prep: cast x -> fp8 interleaved, zero cnt/pool, wcast x3 (bf16) ----------------
// blocks [0,5000): castx ; [5000,5128): W1 ; [5128,5384): W2 ; [5384,5640): W3
__global__ __launch_bounds__(256) void prep_kernel(const float* __restrict__ x,
                                                   unsigned int* __restrict__ xb32,
                                                   int* cnt, float* pool,
                                                   const float* __restrict__ W1,
                                                   const float* __restrict__ W2,
                                                   const float* __restrict__ W3,
                                                   ushort* __restrict__ w1t,
                                                   ushort* __restrict__ w2t,
                                                   ushort* __restrict__ w3t) {
    int bid = blockIdx.x;
    int t = threadIdx.x;
    if (bid < 5000) {
        int i = bid * 256 + t;                // quad index, < 1,280,000
        if (i < NN) cnt[i] = 0;
        if (i < NB * HD) pool[i] = 0.0f;
        size_t g = (size_t)i * 4;
        int b = (i >= (NN * FIN / 4));        // second batch half
        size_t rem = g - (size_t)b * NN * FIN;
        int n = (int)(rem >> 7);              // / FIN
        int f = (int)(rem & (FIN - 1));
        float4 v = *(const float4*)&x[g];
        xb32[(((size_t)n * NB + b) * FIN + f) >> 2] = pk4_fp8(v.x, v.y, v.z, v.w);
    } else {
        const float* W; ushort* WT; int K; int i;
        if (bid < 5128)      { W = W1; WT = w1t; K = FIN; i = (bid - 5000) * 256 + t; }
        else if (bid < 5384) { W = W2; WT = w2t; K = HD;  i = (bid - 5128) * 256 + t; }
        else                 { W = W3; WT = w3t; K = HD;  i = (bid - 5384) * 256 + t; }
        int k = i >> 8, n = i & 255;
        WT[n * K + k] = f2bf(W[i]);
    }
}

// ================= fused layer: agg (fp8 gather -> bf16 LDS A-tile) + MFMA + bias + relu -> fp8 ======
// h: fp8, interleaved rows: node n -> [b0 K-feats | b1 K-feats] (RW = NB*K bytes).
// Block = 1024 threads (16 waves), 32 nodes = 64 A-rows x 256 cols.
// Gather: 2 nodes per wave. MFMA: 4x4 wave grid, wave tile 16 rows x 64 cols.
// BT: weights [HD][K] bf16. C: [MP][HD] fp8 interleaved rows.
template <int K>
__global__ __launch_bounds__(1024, 8) void fused_kernel(const unsigned char* __restrict__ h,
                                                        const ushort* __restrict__ BT,
                                                        const float* __restrict__ bias,
                                                        const int2* __restrict__ edge2,
                                                        const int* __restrict__ rstart,
                                                        const float* __restrict__ dinv,
                                                        unsigned char* __restrict__ C) {
    constexpr int RW = NB * K;            // bytes per node row (256 or 512)
    constexpr int EL = RW / 64;           // bytes (=elems) per lane: 4 or 8
    using VecT = std::conditional_t<EL == 8, uint2, unsigned int>;
    union UV { VecT v; unsigned int u[EL / 4]; };

    __shared__ ushort As[64 * K];         // bf16, swizzled: row*K + ((chunk ^ (row&7))<<3)
    __shared__ ushort Bs[256 * 64];       // bf16, swizzled per k-tile

    int t = threadIdx.x;
    int w = t >> 6, l = t & 63;           // 16 waves
    int n0 = blockIdx.x * 32;
    const unsigned char* hb = h + l * EL; // lane-offset base

    // ---------- phase 1: each wave gathers+aggs 2 nodes, writes bf16 to As ----------
    for (int mi = 0; mi < 2; ++mi) {
        int mloc = w * 2 + mi;            // 0..31
        int n = n0 + mloc;
        float acc[EL];
#pragma unroll
        for (int k = 0; k < EL; ++k) acc[k] = 0.0f;

        if (n < NN) {
            float dn = dinv[n];
            {   // self-loop
                UV s; s.v = *(const VecT*)&hb[(size_t)n * RW];
                float ws = dn * dn;
#pragma unroll
                for (int k = 0; k < EL / 4; ++k) acc4_fp8(acc + 4 * k, s.u[k], ws);
            }
            int e0 = rstart[n], e1 = rstart[n + 1];
            int deg = e1 - e0;            // wave-uniform
            const int2* ep = edge2 + e0;
            int2 mt[12];
            UV r[8];
#pragma unroll
            for (int i = 0; i < 12; ++i) if (i < deg) mt[i] = ep[i];
#pragma unroll
            for (int i = 0; i < 8; ++i) if (i < deg) r[i].v = *(const VecT*)&hb[(size_t)mt[i].x * RW];

            int e = 0;
            for (; e + 4 <= deg; e += 4) {
#pragma unroll
                for (int i = 0; i < 4; ++i) {
                    float ww = __int_as_float(mt[i].y);
#pragma unroll
                    for (int k = 0; k < EL / 4; ++k) acc4_fp8(acc + 4 * k, r[i].u[k], ww);
                }
#pragma unroll
                for (int i = 0; i < 8; ++i) mt[i] = mt[i + 4];
#pragma unroll
                for (int i = 0; i < 4; ++i) r[i] = r[i + 4];
#pragma unroll
                for (int i = 0; i < 4; ++i) if (e + 12 + i < deg) mt[8 + i] = ep[e + 12 + i];
#pragma unroll
                for (int i = 4; i < 8; ++i) if (e + 4 + i < deg) r[i].v = *(const VecT*)&hb[(size_t)mt[i].x * RW];
            }
#pragma unroll
            for (int i = 0; i < 3; ++i) {
                if (e + i < deg) {
                    float ww = __int_as_float(mt[i].y);
#pragma unroll
                    for (int k = 0; k < EL / 4; ++k) acc4_fp8(acc + 4 * k, r[i].u[k], ww);
                }
            }
        }

        // pack acc -> bf16, write swizzled As. A-row = 2*mloc + (l>=32).
        int arow = 2 * mloc + (l >> 5);
        if constexpr (EL == 8) {
            uint4 o;
            o.x = (unsigned int)f2bf(acc[0]) | ((unsigned int)f2bf(acc[1]) << 16);
            o.y = (unsigned int)f2bf(acc[2]) | ((unsigned int)f2bf(acc[3]) << 16);
            o.z = (unsigned int)f2bf(acc[4]) | ((unsigned int)f2bf(acc[5]) << 16);
            o.w = (unsigned int)f2bf(acc[6]) | ((unsigned int)f2bf(acc[7]) << 16);
            *(uint4*)&As[arow * K + (((l & 31) ^ (arow & 7)) << 3)] = o;
        } else {
            uint2 o;
            o.x = (unsigned int)f2bf(acc[0]) | ((unsigned int)f2bf(acc[1]) << 16);
            o.y = (unsigned int)f2bf(acc[2]) | ((unsigned int)f2bf(acc[3]) << 16);
            *(uint2*)&As[arow * K + ((((l & 31) >> 1) ^ (arow & 7)) << 3) + (l & 1) * 4] = o;
        }
    }

    // ---------- phase 2: MFMA over staged As, Bs staged per 64-k tile ----------
    int wr = w >> 2, wc = w & 3;          // 4 x 4 wave grid; wave tile 16 x 64
    f32x4 acc2[4] = {};
    constexpr int NKT = K / 64;
    for (int kt = 0; kt < NKT; ++kt) {
        if (kt > 0) __syncthreads();      // prior MFMA reads of Bs done
#pragma unroll
        for (int i = 0; i < 2; ++i) {
            int c = i * 1024 + t;         // 2048 16B-chunks: 256 rows x 8
            int row = c >> 3, kc = c & 7;
            uint4 v = *(const uint4*)&BT[(size_t)row * K + kt * 64 + kc * 8];
            *(uint4*)&Bs[row * 64 + ((kc ^ (row & 7)) << 3)] = v;
        }
        __syncthreads();                  // publishes Bs (and As on first iter)
#pragma unroll
        for (int s = 0; s < 2; ++s) {
            bf16x8 af, bfr[4];
            {
                int row = wr * 16 + (l & 15);
                int chunk = kt * 8 + s * 4 + (l >> 4);
                af = *(const bf16x8*)&As[row * K + ((chunk ^ (row & 7)) << 3)];
            }
#pragma unroll
            for (int nn = 0; nn < 4; ++nn) {
                int row = wc * 64 + nn * 16 + (l & 15);
                int chunk = s * 4 + (l >> 4);
                bfr[nn] = *(const bf16x8*)&Bs[row * 64 + ((chunk ^ (row & 7)) << 3)];
            }
#pragma unroll
            for (int nn = 0; nn < 4; ++nn)
                acc2[nn] = __builtin_amdgcn_mfma_f32_16x16x32_bf16(af, bfr[nn], acc2[nn], 0, 0, 0);
        }
    }

    // ---------- epilogue: bias + relu + fp8 store ----------
    size_t bm = (size_t)blockIdx.x * 64;
#pragma unroll
    for (int nn = 0; nn < 4; ++nn) {
        int col = wc * 64 + nn * 16 + (l & 15);
        float bv = bias[col];
#pragma unroll
        for (int j = 0; j < 4; ++j) {
            size_t row = bm + wr * 16 + (l >> 4) * 4 + j;
            float v = fmaxf(acc2[nn][j] + bv, 0.0f);
            C[row * HD + col] = f2fp8(v);
        }
    }
}

// ---------------- colsum stage 1: per-block partial sums, no atomics ----------------
// node-group (rows 2n,2n+1) = 512B = 128 uints. Threads 0-127 -> even nodes, 128-255 -> odd.
// partial[block][ (t>>7)*512 + b*256 + f ] fp32
__global__ __launch_bounds__(256) void colsum1_kernel(const unsigned char* __restrict__ h,
                                                      float* __restrict__ partial) {
    const int NCH = 32;                       // nodes per block; 625 blocks
    int n0 = blockIdx.x * NCH;
    int t = threadIdx.x;
    const unsigned int* hu = (const unsigned int*)h;
    int u = t & 127;                          // uint idx within 512B node-group
    int b = u >> 6;                           // batch row within group
    int f0 = (u & 63) * 4;
    float s[4] = {0.f, 0.f, 0.f, 0.f};
    for (int i = 0; i < NCH / 2; ++i) {
        int n = n0 + 2 * i + (t >> 7);
        unsigned int v = hu[(size_t)n * 128 + u];
        f32x2 lo = __builtin_amdgcn_cvt_pk_f32_fp8((int)v, false);
        f32x2 hi = __builtin_amdgcn_cvt_pk_f32_fp8((int)v, true);
        s[0] += lo[0]; s[1] += lo[1]; s[2] += hi[0]; s[3] += hi[1];
    }
    float* pb = partial + (size_t)blockIdx.x * 1024 + (t >> 7) * 512 + b * 256 + f0;
    pb[0] = s[0]; pb[1] = s[1]; pb[2] = s[2]; pb[3] = s[3];
}

// ---------------- colsum stage 2: reduce partials [625][1024] -> pool[512] ----------------
__global__ __launch_bounds__(256) void colsum2_kernel(const float* __restrict__ partial,
                                                      float* __restrict__ pool) {
    int idx = blockIdx.x * 256 + threadIdx.x;     // 0..1023 (4 blocks in x)
    int r0 = blockIdx.y * 40;                      // 16 chunks of 40 rows
    int r1 = min(r0 + 40, 625);
    float s = 0.0f;
    for (int r = r0; r < r1; ++r) s += partial[(size_t)r * 1024 + idx];
    atomicAdd(&pool[idx & 511], s);
}

// ---------------- head: out[b] = mean_h . Wl + bl ----------------
__global__ __launch_bounds__(256) void head_kernel(const float* __restrict__ pool,
                                                   const float* __restrict__ Wl,
                                                   const float* __restrict__ bl,
                                                   float* __restrict__ out) {
    __shared__ double red[256];
    int f = threadIdx.x;
    for (int b = 0; b < NB; ++b) {
        double v = (double)pool[b * HD + f] * (1.0 / NN) * (double)Wl[f];
        red[f] = v;
        __syncthreads();
        for (int off = 128; off; off >>= 1) {
            if (f < off) red[f] += red[f + off];
            __syncthreads();
        }
        if (f == 0) out[b] = (float)(red[0] + (double)bl[0]);
        __syncthreads();
    }
}

extern "C" void kernel_launch(void* const* d_in, const int* in_sizes, int n_in,
                              void* d_out, int out_size, void* d_ws, size_t ws_size,
                              hipStream_t stream) {
    const float* x  = (const float*)d_in[0];
    const int* eidx = (const int*)d_in[1];
    const float* W1 = (const float*)d_in[2];
    const float* b1 = (const float*)d_in[3];
    const float* W2 = (const float*)d_in[4];
    const float* b2 = (const float*)d_in[5];
    const float* W3 = (const float*)d_in[6];
    const float* b3 = (const float*)d_in[7];
    const float* Wl = (const float*)d_in[8];
    const float* bl = (const float*)d_in[9];
    float* out = (float*)d_out;

    const int* src = eidx;
    const int* dst = eidx + NE;

    // ---- workspace layout (bytes, 256B-aligned blocks) ----
    char* p = (char*)d_ws;
    auto alloc = [&](size_t bytes) { char* r = p; p += (bytes + 255) & ~(size_t)255; return r; };
    unsigned char* xb   = (unsigned char*)alloc((size_t)MP * FIN);   // fp8
    unsigned char* bufA = (unsigned char*)alloc((size_t)MP * HD);    // fp8
    unsigned char* bufB = (unsigned char*)alloc((size_t)MP * HD);    // fp8
    ushort* w1t   = (ushort*)alloc((size_t)HD * FIN * 2);
    ushort* w2t   = (ushort*)alloc((size_t)HD * HD * 2);
    ushort* w3t   = (ushort*)alloc((size_t)HD * HD * 2);
    float*  dinv  = (float*)alloc(NN * 4);
    int2*   edge2 = (int2*)alloc((size_t)NE * 8);
    int*    cnt   = (int*)alloc(NN * 4);
    int*    rstart= (int*)alloc((NN + 1) * 4);
    int*    bsum  = (int*)alloc(SB * 4);
    float*  partial = (float*)alloc((size_t)625 * 1024 * 4);
    float*  pool  = (float*)alloc(NB * HD * 4);

    // prep: castx (+ zero cnt/pool) + all weight casts
    prep_kernel<<<5640, 256, 0, stream>>>(x, (unsigned int*)xb, cnt, pool, W1, W2, W3, w1t, w2t, w3t);
    count_kernel<<<(NE + 255) / 256, 256, 0, stream>>>(dst, cnt);
    scan_blk_kernel<<<SB, 256, 0, stream>>>(cnt, bsum, dinv);
    scan_fin_kernel<<<SB, 256, 0, stream>>>(bsum, cnt, rstart);
    bucket_kernel<<<(NE + 255) / 256, 256, 0, stream>>>(src, dst, cnt, edge2, dinv);

    const int FG = MP / 64;   // 626 blocks

    // layer 1: bufA = relu(agg(xb) @ W1 + b1)
    fused_kernel<FIN><<<FG, 1024, 0, stream>>>(xb, w1t, b1, edge2, rstart, dinv, bufA);
    // layer 2: bufB = relu(agg(bufA) @ W2 + b2)
    fused_kernel<HD><<<FG, 1024, 0, stream>>>(bufA, w2t, b2, edge2, rstart, dinv, bufB);
    // layer 3: bufA = relu(agg(bufB) @ W3 + b3)
    fused_kernel<HD><<<FG, 1024, 0, stream>>>(bufB, w3t, b3, edge2, rstart, dinv, bufA);

    // mean pool + head
    colsum1_kernel<<<NN / 32, 256, 0, stream>>>(bufA, partial);
    colsum2_kernel<<<dim3(4, 16), 256, 0, stream>>>(partial, pool);
    head_kernel<<<1, 256, 0, stream>>>(pool, Wl, bl, out);
}

// Round 11
// 295.362 us; speedup vs baseline: 1.6241x; 1.6241x over previous
//
#include <hip/hip_runtime.h>
#include <hip/hip_bf16.h>
#include <type_traits>

#define NN 20000      // nodes
#define NE 320000     // edges
#define HD 256        // hidden dim
#define NB 2          // batch
#define FIN 128
#define MP 40064      // NB*NN padded to multiple of 128 (313*128)
#define SB 79         // scan blocks = ceil(NN/256)

typedef __attribute__((ext_vector_type(8))) short bf16x8;
typedef __attribute__((ext_vector_type(4))) float f32x4;
typedef __attribute__((ext_vector_type(2))) float f32x2;

__device__ inline ushort f2bf(float f) {
    __hip_bfloat16 h = __float2bfloat16(f);
    return *reinterpret_cast<ushort*>(&h);
}
// fp8 e4m3 (OCP on gfx950) helpers
__device__ inline unsigned int pk4_fp8(float a, float b, float c, float d) {
    int r = __builtin_amdgcn_cvt_pk_fp8_f32(a, b, 0, false);
    r = __builtin_amdgcn_cvt_pk_fp8_f32(c, d, r, true);
    return (unsigned int)r;
}
__device__ inline void acc4_fp8(float* acc, unsigned int u, float w) {
    f32x2 lo = __builtin_amdgcn_cvt_pk_f32_fp8((int)u, false);
    f32x2 hi = __builtin_amdgcn_cvt_pk_f32_fp8((int)u, true);
    acc[0] += w * lo[0]; acc[1] += w * lo[1];
    acc[2] += w * hi[0]; acc[3] += w * hi[1];
}
__device__ inline unsigned char f2fp8(float v) {
    return (unsigned char)(__builtin_amdgcn_cvt_pk_fp8_f32(v, v, 0, false) & 0xff);
}

// ---------------- count incoming edges per dst ----------------
__global__ __launch_bounds__(256) void count_kernel(const int* __restrict__ dst, int* cnt) {
    int e = blockIdx.x * 256 + threadIdx.x;
    if (e < NE) atomicAdd(&cnt[dst[e]], 1);
}

// ---------------- scan stage 1: per-block sums + dinv ----------------
__global__ __launch_bounds__(256) void scan_blk_kernel(const int* __restrict__ cnt,
                                                       int* __restrict__ bsum,
                                                       float* __restrict__ dinv) {
    __shared__ int s[256];
    int t = threadIdx.x, b = blockIdx.x;
    int n = b * 256 + t;
    int c = (n < NN) ? cnt[n] : 0;
    if (n < NN) dinv[n] = rsqrtf(1.0f + (float)c);
    s[t] = c;
    __syncthreads();
    for (int off = 128; off; off >>= 1) {
        if (t < off) s[t] += s[t + off];
        __syncthreads();
    }
    if (t == 0) bsum[b] = s[0];
}

// ---------------- scan stage 2: block offset + intra-block exclusive scan ----------------
__global__ __launch_bounds__(256) void scan_fin_kernel(const int* __restrict__ bsum,
                                                       int* __restrict__ cnt,
                                                       int* __restrict__ rstart) {
    __shared__ int sb[128];
    __shared__ int s[256];
    int t = threadIdx.x, b = blockIdx.x;
    if (t < 128) sb[t] = (t < SB) ? bsum[t] : 0;
    __syncthreads();
    for (int off = 1; off < 128; off <<= 1) {
        int v = (t < 128 && t >= off) ? sb[t - off] : 0;
        __syncthreads();
        if (t < 128) sb[t] += v;
        __syncthreads();
    }
    int boff = (b == 0) ? 0 : sb[b - 1];
    int n = b * 256 + t;
    int c = (n < NN) ? cnt[n] : 0;
    s[t] = c;
    __syncthreads();
    for (int off = 1; off < 256; off <<= 1) {
        int v = (t >= off) ? s[t - off] : 0;
        __syncthreads();
        s[t] += v;
        __syncthreads();
    }
    int excl = s[t] - c + boff;
    if (n < NN) { rstart[n] = excl; cnt[n] = excl; }   // cnt becomes bucket cursor
    if (b == 0 && t == 0) rstart[NN] = NE;
}

// ---------------- bucket edges by dst, precompute weights ----------------
__global__ __launch_bounds__(256) void bucket_kernel(const int* __restrict__ src,
                                                     const int* __restrict__ dst,
                                                     int* cursor, int2* edge2,
                                                     const float* __restrict__ dinv) {
    int e = blockIdx.x * 256 + threadIdx.x;
    if (e >= NE) return;
    int s = src[e], d = dst[e];
    int pos = atomicAdd(&cursor[d], 1);
    float w = dinv[s] * dinv[d];
    edge2[pos] = make_int2(s, __float_as_int(w));
}

// ---------------- fused prep: cast x -> fp8 interleaved, zero cnt/pool, wcast x3 (bf16) ----------------
// blocks [0,5000): castx ; [5000,5128): W1 ; [5128,5384): W2 ; [5384,5640): W3
__global__ __launch_bounds__(256) void prep_kernel(const float* __restrict__ x,
                                                   unsigned int* __restrict__ xb32,
                                                   int* cnt, float* pool,
                                                   const float* __restrict__ W1,
                                                   const float* __restrict__ W2,
                                                   const float* __restrict__ W3,
                                                   ushort* __restrict__ w1t,
                                                   ushort* __restrict__ w2t,
                                                   ushort* __restrict__ w3t) {
    int bid = blockIdx.x;
    int t = threadIdx.x;
    if (bid < 5000) {
        int i = bid * 256 + t;                // quad index, < 1,280,000
        if (i < NN) cnt[i] = 0;
        if (i < NB * HD) pool[i] = 0.0f;
        size_t g = (size_t)i * 4;
        int b = (i >= (NN * FIN / 4));        // second batch half
        size_t rem = g - (size_t)b * NN * FIN;
        int n = (int)(rem >> 7);              // / FIN
        int f = (int)(rem & (FIN - 1));
        float4 v = *(const float4*)&x[g];
        xb32[(((size_t)n * NB + b) * FIN + f) >> 2] = pk4_fp8(v.x, v.y, v.z, v.w);
    } else {
        const float* W; ushort* WT; int K; int i;
        if (bid < 5128)      { W = W1; WT = w1t; K = FIN; i = (bid - 5000) * 256 + t; }
        else if (bid < 5384) { W = W2; WT = w2t; K = HD;  i = (bid - 5128) * 256 + t; }
        else                 { W = W3; WT = w3t; K = HD;  i = (bid - 5384) * 256 + t; }
        int k = i >> 8, n = i & 255;
        WT[n * K + k] = f2bf(W[i]);
    }
}

// ================= fused layer: agg (fp8 gather -> bf16 LDS A-tile) + MFMA + bias + relu -> fp8 ======
// h: fp8, interleaved rows: node n -> [b0 K-feats | b1 K-feats] (RW = NB*K bytes).
// Block = 512 threads (8 waves), 32 nodes = 64 A-rows x 256 cols.
// As bf16 (32KB @ K=256) + Bs 32-k tile (16KB) = 48KB -> 3 blocks/CU.
// BT: weights [HD][K] bf16. C: [MP][HD] fp8 interleaved rows.
template <int K>
__global__ __launch_bounds__(512, 4) void fused_kernel(const unsigned char* __restrict__ h,
                                                       const ushort* __restrict__ BT,
                                                       const float* __restrict__ bias,
                                                       const int2* __restrict__ edge2,
                                                       const int* __restrict__ rstart,
                                                       const float* __restrict__ dinv,
                                                       unsigned char* __restrict__ C) {
    constexpr int RW = NB * K;            // bytes per node row (256 or 512)
    constexpr int EL = RW / 64;           // bytes (=elems) per lane: 4 or 8
    using VecT = std::conditional_t<EL == 8, uint2, unsigned int>;
    union UV { VecT v; unsigned int u[EL / 4]; };

    __shared__ ushort As[64 * K];         // bf16, swizzled: row*K + ((chunk ^ (row&7))<<3)
    __shared__ ushort Bs[256 * 32];       // bf16, one 32-k tile, swizzled

    int t = threadIdx.x;
    int w = t >> 6, l = t & 63;
    int n0 = blockIdx.x * 32;
    const unsigned char* hb = h + l * EL; // lane-offset base

    // ---------- phase 1: each wave gathers+aggs 4 nodes, writes bf16 to As ----------
    for (int mi = 0; mi < 4; ++mi) {
        int mloc = w * 4 + mi;            // 0..31
        int n = n0 + mloc;
        float acc[EL];
#pragma unroll
        for (int k = 0; k < EL; ++k) acc[k] = 0.0f;

        if (n < NN) {
            float dn = dinv[n];
            {   // self-loop
                UV s; s.v = *(const VecT*)&hb[(size_t)n * RW];
                float ws = dn * dn;
#pragma unroll
                for (int k = 0; k < EL / 4; ++k) acc4_fp8(acc + 4 * k, s.u[k], ws);
            }
            int e0 = rstart[n], e1 = rstart[n + 1];
            int deg = e1 - e0;            // wave-uniform
            const int2* ep = edge2 + e0;
            int2 mt[12];
            UV r[8];
#pragma unroll
            for (int i = 0; i < 12; ++i) if (i < deg) mt[i] = ep[i];
#pragma unroll
            for (int i = 0; i < 8; ++i) if (i < deg) r[i].v = *(const VecT*)&hb[(size_t)mt[i].x * RW];

            int e = 0;
            for (; e + 4 <= deg; e += 4) {
#pragma unroll
                for (int i = 0; i < 4; ++i) {
                    float ww = __int_as_float(mt[i].y);
#pragma unroll
                    for (int k = 0; k < EL / 4; ++k) acc4_fp8(acc + 4 * k, r[i].u[k], ww);
                }
#pragma unroll
                for (int i = 0; i < 8; ++i) mt[i] = mt[i + 4];
#pragma unroll
                for (int i = 0; i < 4; ++i) r[i] = r[i + 4];
#pragma unroll
                for (int i = 0; i < 4; ++i) if (e + 12 + i < deg) mt[8 + i] = ep[e + 12 + i];
#pragma unroll
                for (int i = 4; i < 8; ++i) if (e + 4 + i < deg) r[i].v = *(const VecT*)&hb[(size_t)mt[i].x * RW];
            }
#pragma unroll
            for (int i = 0; i < 3; ++i) {
                if (e + i < deg) {
                    float ww = __int_as_float(mt[i].y);
#pragma unroll
                    for (int k = 0; k < EL / 4; ++k) acc4_fp8(acc + 4 * k, r[i].u[k], ww);
                }
            }
        }

        // pack acc -> bf16, write swizzled As. A-row = 2*mloc + (l>=32).
        int arow = 2 * mloc + (l >> 5);
        if constexpr (EL == 8) {
            uint4 o;
            o.x = (unsigned int)f2bf(acc[0]) | ((unsigned int)f2bf(acc[1]) << 16);
            o.y = (unsigned int)f2bf(acc[2]) | ((unsigned int)f2bf(acc[3]) << 16);
            o.z = (unsigned int)f2bf(acc[4]) | ((unsigned int)f2bf(acc[5]) << 16);
            o.w = (unsigned int)f2bf(acc[6]) | ((unsigned int)f2bf(acc[7]) << 16);
            *(uint4*)&As[arow * K + (((l & 31) ^ (arow & 7)) << 3)] = o;
        } else {
            uint2 o;
            o.x = (unsigned int)f2bf(acc[0]) | ((unsigned int)f2bf(acc[1]) << 16);
            o.y = (unsigned int)f2bf(acc[2]) | ((unsigned int)f2bf(acc[3]) << 16);
            *(uint2*)&As[arow * K + ((((l & 31) >> 1) ^ (arow & 7)) << 3) + (l & 1) * 4] = o;
        }
    }

    // ---------- phase 2: MFMA; Bs staged per 32-k tile ----------
    int wr = w >> 2, wc = w & 3;          // 2 x 4 wave grid; wave tile 32 x 64
    f32x4 acc2[2][4] = {};
    constexpr int NKT = K / 32;
    for (int kt = 0; kt < NKT; ++kt) {
        if (kt > 0) __syncthreads();      // prior MFMA reads of Bs done
#pragma unroll
        for (int i = 0; i < 2; ++i) {
            int c = i * 512 + t;          // 1024 16B-chunks: 256 rows x 4
            int row = c >> 2, kc = c & 3;
            uint4 v = *(const uint4*)&BT[(size_t)row * K + kt * 32 + kc * 8];
            *(uint4*)&Bs[row * 32 + ((kc ^ (row & 3)) << 3)] = v;
        }
        __syncthreads();                  // publishes Bs (and As on first iter)
        bf16x8 af[2], bfr[4];
#pragma unroll
        for (int m = 0; m < 2; ++m) {
            int row = wr * 32 + m * 16 + (l & 15);
            int chunk = kt * 4 + (l >> 4);
            af[m] = *(const bf16x8*)&As[row * K + ((chunk ^ (row & 7)) << 3)];
        }
#pragma unroll
        for (int nn = 0; nn < 4; ++nn) {
            int row = wc * 64 + nn * 16 + (l & 15);
            bfr[nn] = *(const bf16x8*)&Bs[row * 32 + (((l >> 4) ^ (row & 3)) << 3)];
        }
#pragma unroll
        for (int m = 0; m < 2; ++m)
#pragma unroll
            for (int nn = 0; nn < 4; ++nn)
                acc2[m][nn] = __builtin_amdgcn_mfma_f32_16x16x32_bf16(af[m], bfr[nn], acc2[m][nn], 0, 0, 0);
    }

    // ---------- epilogue: bias + relu + fp8 store ----------
    size_t bm = (size_t)blockIdx.x * 64;
#pragma unroll
    for (int m = 0; m < 2; ++m) {
#pragma unroll
        for (int nn = 0; nn < 4; ++nn) {
            int col = wc * 64 + nn * 16 + (l & 15);
            float bv = bias[col];
#pragma unroll
            for (int j = 0; j < 4; ++j) {
                size_t row = bm + wr * 32 + m * 16 + (l >> 4) * 4 + j;
                float v = fmaxf(acc2[m][nn][j] + bv, 0.0f);
                C[row * HD + col] = f2fp8(v);
            }
        }
    }
}

// ---------------- colsum stage 1: per-block partial sums, no atomics ----------------
__global__ __launch_bounds__(256) void colsum1_kernel(const unsigned char* __restrict__ h,
                                                      float* __restrict__ partial) {
    const int NCH = 32;                       // nodes per block; 625 blocks
    int n0 = blockIdx.x * NCH;
    int t = threadIdx.x;
    const unsigned int* hu = (const unsigned int*)h;
    int u = t & 127;                          // uint idx within 512B node-group
    int b = u >> 6;                           // batch row within group
    int f0 = (u & 63) * 4;
    float s[4] = {0.f, 0.f, 0.f, 0.f};
    for (int i = 0; i < NCH / 2; ++i) {
        int n = n0 + 2 * i + (t >> 7);
        unsigned int v = hu[(size_t)n * 128 + u];
        f32x2 lo = __builtin_amdgcn_cvt_pk_f32_fp8((int)v, false);
        f32x2 hi = __builtin_amdgcn_cvt_pk_f32_fp8((int)v, true);
        s[0] += lo[0]; s[1] += lo[1]; s[2] += hi[0]; s[3] += hi[1];
    }
    float* pb = partial + (size_t)blockIdx.x * 1024 + (t >> 7) * 512 + b * 256 + f0;
    pb[0] = s[0]; pb[1] = s[1]; pb[2] = s[2]; pb[3] = s[3];
}

// ---------------- colsum stage 2: reduce partials [625][1024] -> pool[512] ----------------
__global__ __launch_bounds__(256) void colsum2_kernel(const float* __restrict__ partial,
                                                      float* __restrict__ pool) {
    int idx = blockIdx.x * 256 + threadIdx.x;     // 0..1023
    int r0 = blockIdx.y * 40;
    int r1 = min(r0 + 40, 625);
    float s = 0.0f;
    for (int r = r0; r < r1; ++r) s += partial[(size_t)r * 1024 + idx];
    atomicAdd(&pool[idx & 511], s);
}

// ---------------- head: out[b] = mean_h . Wl + bl ----------------
__global__ __launch_bounds__(256) void head_kernel(const float* __restrict__ pool,
                                                   const float* __restrict__ Wl,
                                                   const float* __restrict__ bl,
                                                   float* __restrict__ out) {
    __shared__ double red[256];
    int f = threadIdx.x;
    for (int b = 0; b < NB; ++b) {
        double v = (double)pool[b * HD + f] * (1.0 / NN) * (double)Wl[f];
        red[f] = v;
        __syncthreads();
        for (int off = 128; off; off >>= 1) {
            if (f < off) red[f] += red[f + off];
            __syncthreads();
        }
        if (f == 0) out[b] = (float)(red[0] + (double)bl[0]);
        __syncthreads();
    }
}

extern "C" void kernel_launch(void* const* d_in, const int* in_sizes, int n_in,
                              void* d_out, int out_size, void* d_ws, size_t ws_size,
                              hipStream_t stream) {
    const float* x  = (const float*)d_in[0];
    const int* eidx = (const int*)d_in[1];
    const float* W1 = (const float*)d_in[2];
    const float* b1 = (const float*)d_in[3];
    const float* W2 = (const float*)d_in[4];
    const float* b2 = (const float*)d_in[5];
    const float* W3 = (const float*)d_in[6];
    const float* b3 = (const float*)d_in[7];
    const float* Wl = (const float*)d_in[8];
    const float* bl = (const float*)d_in[9];
    float* out = (float*)d_out;

    const int* src = eidx;
    const int* dst = eidx + NE;

    // ---- workspace layout (bytes, 256B-aligned blocks) ----
    char* p = (char*)d_ws;
    auto alloc = [&](size_t bytes) { char* r = p; p += (bytes + 255) & ~(size_t)255; return r; };
    unsigned char* xb   = (unsigned char*)alloc((size_t)MP * FIN);   // fp8
    unsigned char* bufA = (unsigned char*)alloc((size_t)MP * HD);    // fp8
    unsigned char* bufB = (unsigned char*)alloc((size_t)MP * HD);    // fp8
    ushort* w1t   = (ushort*)alloc((size_t)HD * FIN * 2);
    ushort* w2t   = (ushort*)alloc((size_t)HD * HD * 2);
    ushort* w3t   = (ushort*)alloc((size_t)HD * HD * 2);
    float*  dinv  = (float*)alloc(NN * 4);
    int2*   edge2 = (int2*)alloc((size_t)NE * 8);
    int*    cnt   = (int*)alloc(NN * 4);
    int*    rstart= (int*)alloc((NN + 1) * 4);
    int*    bsum  = (int*)alloc(SB * 4);
    float*  partial = (float*)alloc((size_t)625 * 1024 * 4);
    float*  pool  = (float*)alloc(NB * HD * 4);

    // prep: castx (+ zero cnt/pool) + all weight casts
    prep_kernel<<<5640, 256, 0, stream>>>(x, (unsigned int*)xb, cnt, pool, W1, W2, W3, w1t, w2t, w3t);
    count_kernel<<<(NE + 255) / 256, 256, 0, stream>>>(dst, cnt);
    scan_blk_kernel<<<SB, 256, 0, stream>>>(cnt, bsum, dinv);
    scan_fin_kernel<<<SB, 256, 0, stream>>>(bsum, cnt, rstart);
    bucket_kernel<<<(NE + 255) / 256, 256, 0, stream>>>(src, dst, cnt, edge2, dinv);

    const int FG = MP / 64;   // 626 blocks

    // layer 1: bufA = relu(agg(xb) @ W1 + b1)
    fused_kernel<FIN><<<FG, 512, 0, stream>>>(xb, w1t, b1, edge2, rstart, dinv, bufA);
    // layer 2: bufB = relu(agg(bufA) @ W2 + b2)
    fused_kernel<HD><<<FG, 512, 0, stream>>>(bufA, w2t, b2, edge2, rstart, dinv, bufB);
    // layer 3: bufA = relu(agg(bufB) @ W3 + b3)
    fused_kernel<HD><<<FG, 512, 0, stream>>>(bufB, w3t, b3, edge2, rstart, dinv, bufA);

    // mean pool + head
    colsum1_kernel<<<NN / 32, 256, 0, stream>>>(bufA, partial);
    colsum2_kernel<<<dim3(4, 16), 256, 0, stream>>>(partial, pool);
    head_kernel<<<1, 256, 0, stream>>>(pool, Wl, bl, out);
}